// Round 13
// baseline (347.316 us; speedup 1.0000x reference)
//
#include <hip/hip_runtime.h>
#include <math.h>

#define S_LEN 2048
#define BATCH 2
#define EMB 768
#define NH 8
#define HD 96
#define NTOK (BATCH*S_LEN)
#define RSQRT_D 0.10206207261596575f   // 1/sqrt(96)

typedef unsigned short u16;
typedef __attribute__((ext_vector_type(8))) short bf16x8;
typedef __attribute__((ext_vector_type(4))) float f32x4;

#define MFMA16(a,b,c) __builtin_amdgcn_mfma_f32_16x16x32_bf16(a,b,c,0,0,0)

__device__ __forceinline__ u16 f2bf(float f){
    unsigned u = __float_as_uint(f);
    return (u16)((u + 0x7fffu + ((u>>16)&1u)) >> 16);
}
__device__ __forceinline__ float bf2f(unsigned u){
    return __uint_as_float(u << 16);
}

union U16x8 { u16 u[8]; float4 f4; };
union U16x4 { u16 u[4]; uint2 v2; };

// ---------------------------------------------------------------------------
// f32 -> bf16 elementwise convert (vectorized x4)
// ---------------------------------------------------------------------------
__global__ __launch_bounds__(256) void cvt_bf16_kernel(
    const float* __restrict__ src, u16* __restrict__ dst, int n4)
{
    int i = blockIdx.x * 256 + threadIdx.x;
    if (i < n4) {
        float4 v = ((const float4*)src)[i];
        U16x4 o;
        o.u[0] = f2bf(v.x); o.u[1] = f2bf(v.y); o.u[2] = f2bf(v.z); o.u[3] = f2bf(v.w);
        *(uint2*)(dst + (size_t)i*4) = o.v2;
    }
}

// ---------------------------------------------------------------------------
// W[768][768] f32 -> Wt[n][k] bf16 (transpose + convert). grid (12,12), 256thr
// ---------------------------------------------------------------------------
__global__ __launch_bounds__(256) void transcvt_kernel(
    const float* __restrict__ W, u16* __restrict__ Wt)
{
    __shared__ float T[64][65];
    const int t = threadIdx.x;
    const int k0 = blockIdx.y * 64, n0 = blockIdx.x * 64;
    #pragma unroll
    for (int i = 0; i < 4; ++i) {
        int idx = t + 256*i;
        int r = idx >> 4, c4 = idx & 15;
        float4 v = *(const float4*)(W + (size_t)(k0 + r)*EMB + n0 + c4*4);
        T[r][c4*4+0] = v.x; T[r][c4*4+1] = v.y; T[r][c4*4+2] = v.z; T[r][c4*4+3] = v.w;
    }
    __syncthreads();
    #pragma unroll
    for (int i = 0; i < 2; ++i) {
        int idx = t + 256*i;
        int n = idx >> 3, c = idx & 7;
        U16x8 o;
        #pragma unroll
        for (int e = 0; e < 8; ++e) o.u[e] = f2bf(T[c*8+e][n]);
        *(float4*)(Wt + (size_t)(n0 + n)*EMB + k0 + c*8) = o.f4;
    }
}

// ---------------------------------------------------------------------------
// QKV projection MFMA (unchanged)
// ---------------------------------------------------------------------------
__global__ __launch_bounds__(256) void qkv_mfma_kernel(
    const u16* __restrict__ hsb,
    const u16* __restrict__ WqT, const float* __restrict__ bq,
    const u16* __restrict__ WkT, const float* __restrict__ bk,
    const u16* __restrict__ WvT, const float* __restrict__ bv,
    u16* __restrict__ qo, u16* __restrict__ ko, u16* __restrict__ vo)
{
    const u16* Wt; const float* bias; u16* out;
    if (blockIdx.z == 0)      { Wt = WqT; bias = bq; out = qo; }
    else if (blockIdx.z == 1) { Wt = WkT; bias = bk; out = ko; }
    else                      { Wt = WvT; bias = bv; out = vo; }

    __shared__ __align__(16) u16 As[64*64];
    __shared__ __align__(16) u16 Bs[64*64];
    const int tid = threadIdx.x;
    const int w = tid >> 6, lane = tid & 63, lh = lane & 15, g = lane >> 4;
    const int wm = w >> 1, wn = w & 1;
    const int row0 = blockIdx.y * 64, col0 = blockIdx.x * 64;

    f32x4 acc[2][2];
    #pragma unroll
    for (int i = 0; i < 2; ++i)
        #pragma unroll
        for (int j = 0; j < 2; ++j) acc[i][j] = (f32x4){0.f,0.f,0.f,0.f};

    for (int k0 = 0; k0 < EMB; k0 += 64) {
        __syncthreads();
        #pragma unroll
        for (int i = 0; i < 2; ++i) {
            int idx = tid + 256*i;
            int r = idx >> 3, c = idx & 7;
            float4 a4 = *(const float4*)(hsb + (size_t)(row0 + r)*EMB + k0 + c*8);
            *(float4*)(As + ((size_t)r*8 + (c ^ (r & 7)))*8) = a4;
            float4 b4 = *(const float4*)(Wt + (size_t)(col0 + r)*EMB + k0 + c*8);
            *(float4*)(Bs + ((size_t)r*8 + (c ^ (r & 7)))*8) = b4;
        }
        __syncthreads();
        bf16x8 af[2][2], bfr[2][2];
        #pragma unroll
        for (int mt = 0; mt < 2; ++mt)
            #pragma unroll
            for (int kk = 0; kk < 2; ++kk) {
                int r = wm*32 + mt*16 + lh;
                af[mt][kk] = *(const bf16x8*)(As + ((size_t)r*8 + ((kk*4+g) ^ (lh & 7)))*8);
            }
        #pragma unroll
        for (int nt = 0; nt < 2; ++nt)
            #pragma unroll
            for (int kk = 0; kk < 2; ++kk) {
                int r = wn*32 + nt*16 + lh;
                bfr[nt][kk] = *(const bf16x8*)(Bs + ((size_t)r*8 + ((kk*4+g) ^ (lh & 7)))*8);
            }
        #pragma unroll
        for (int mt = 0; mt < 2; ++mt)
            #pragma unroll
            for (int nt = 0; nt < 2; ++nt)
                #pragma unroll
                for (int kk = 0; kk < 2; ++kk)
                    acc[mt][nt] = MFMA16(af[mt][kk], bfr[nt][kk], acc[mt][nt]);
    }

    #pragma unroll
    for (int mt = 0; mt < 2; ++mt)
        #pragma unroll
        for (int nt = 0; nt < 2; ++nt)
            #pragma unroll
            for (int r = 0; r < 4; ++r) {
                int tt = row0 + wm*32 + mt*16 + g*4 + r;
                int o  = col0 + wn*32 + nt*16 + lh;
                float val = acc[mt][nt][r] + bias[o];
                int b = tt >> 11, s = tt & (S_LEN - 1);
                int h = o / HD, d = o - h*HD;
                out[((size_t)(b*NH + h)*S_LEN + s)*HD + d] = f2bf(val);
            }
}

// ---------------------------------------------------------------------------
// V transpose: vb[B,H,S,D] bf16 -> vt[B,H,D,S] bf16 (unchanged)
// ---------------------------------------------------------------------------
__global__ __launch_bounds__(256) void vtrans_kernel(
    const u16* __restrict__ vb, u16* __restrict__ vt)
{
    const int bh = blockIdx.y;
    const int s0 = blockIdx.x * 64;
    __shared__ __align__(16) u16 T[64*96];
    const int t = threadIdx.x;
    #pragma unroll
    for (int i = 0; i < 3; ++i) {
        int idx = t + 256*i;
        int s = idx / 12, c = idx % 12;
        float4 v = *(const float4*)(vb + ((size_t)bh*S_LEN + s0 + s)*HD + c*8);
        *(float4*)(T + ((size_t)s*12 + c)*8) = v;
    }
    __syncthreads();
    #pragma unroll
    for (int i = 0; i < 3; ++i) {
        int idx = t + 256*i;
        int d = idx >> 3, c = idx & 7;
        U16x8 o;
        #pragma unroll
        for (int e = 0; e < 8; ++e) o.u[e] = T[(size_t)(c*8+e)*HD + d];
        *(float4*)(vt + ((size_t)bh*HD + d)*S_LEN + s0 + c*8) = o.f4;
    }
}

// ---------------------------------------------------------------------------
// FUSED attention v4: QBLK=32, 512 thr, KTILE=128 -> 16 iterations/phase.
// Halves barrier count vs round 10 and doubles per-iteration compute window
// for the prefetched K/V loads. Wave-local 16x16 patch epilogue (no block
// barrier). LDS: Us 128K + KV 24K + patches 8K = 163,840 B exactly.
// ---------------------------------------------------------------------------
__global__ __launch_bounds__(512) void fused_attn_kernel(
    const u16* __restrict__ qbf, const u16* __restrict__ kbf,
    const u16* __restrict__ vt,
    const float* __restrict__ dist, const float* __restrict__ ang,
    const float* __restrict__ mask,
    const float* __restrict__ pdw, const float* __restrict__ pdb,
    const float* __restrict__ paw, const float* __restrict__ pab,
    float* __restrict__ probs, u16* __restrict__ ctxb)
{
    const int bh = blockIdx.y, b = bh >> 3, h = bh & 7;
    const int q0 = blockIdx.x * 32;
    const int tid = threadIdx.x;
    const int lane = tid & 63, w = tid >> 6, lh = lane & 15, g = lane >> 4;
    const int rt = w >> 2;              // row-tile (0,1)
    const int ct = w & 3;               // col-tile base (QK) / d-tile base (PV)

    __shared__ __align__(16) u16 Us[32*2048];    // 128 KB u stripe (32 subtiles of 64)
    __shared__ __align__(16) u16 KV[128*96];     // 24 KB: K tile 128x96 / V tile 96x128
    __shared__ __align__(16) float Sfw[8*256];   // 8 KB per-wave patches; Qtmp in prologue

    // ---- prologue: stage Q (into Sfw region) and K tile 0 ----
    u16* Qtmp = (u16*)Sfw;
    if (tid < 384) {
        int r = tid / 12, c = tid % 12;
        float4 v = *(const float4*)(qbf + ((size_t)bh*S_LEN + q0 + r)*HD + c*8);
        *(float4*)(Qtmp + ((size_t)r*12 + (c ^ ((r >> 1) & 3)))*8) = v;
    }
    #pragma unroll
    for (int i = 0; i < 3; ++i) {
        int idx = tid + 512*i;
        int r = idx / 12, c = idx - (idx/12)*12;
        float4 v = *(const float4*)(kbf + ((size_t)bh*S_LEN + r)*HD + c*8);
        *(float4*)(KV + ((size_t)r*12 + (c ^ ((r >> 1) & 3)))*8) = v;
    }
    __syncthreads();
    bf16x8 qf[3];
    #pragma unroll
    for (int kk = 0; kk < 3; ++kk) {
        int r = rt*16 + lh;
        qf[kk] = *(const bf16x8*)(Qtmp + ((size_t)r*12 + ((kk*4+g) ^ ((r >> 1) & 3)))*8);
    }
    __syncthreads();   // release Qtmp region for patches

    const float DW = *pdw, AW = *paw, CB = *pdb + *pab;

    // wave-local epilogue coords
    const int prow = lane >> 2;         // 0..15 patch row
    const int pc   = lane & 3;          // float4 chunk within 16 cols
    const int erow = rt*16 + prow;      // tile row 0..31
    const size_t drowbase = ((size_t)b*S_LEN + q0 + erow)*S_LEN;
    const int ecol = ct*16 + pc*4;      // col within first 64-half of the 128 tile
    const int uoffA = (erow*8 + ((ct*2 + (pc>>1)) ^ (erow & 7)))*8 + (pc & 1)*4;
    float* Sfme = Sfw + w*256;

    float lpart = 0.f;

    // ================= Phase A: QK^T (128 cols/iter) -> u into LDS ==========
    for (int kt = 0; kt < 16; ++kt) {
        // prefetch K(kt+1) into regs
        float4 kreg[3];
        if (kt < 15) {
            #pragma unroll
            for (int i = 0; i < 3; ++i) {
                int idx = tid + 512*i;
                int r = idx / 12, c = idx - (idx/12)*12;
                kreg[i] = *(const float4*)(kbf + ((size_t)bh*S_LEN + (kt+1)*128 + r)*HD + c*8);
            }
        }
        // bias/mask for this kt (two 64-col halves)
        float4 d40 = *(const float4*)(dist + drowbase + kt*128 + ecol);
        float4 g40 = *(const float4*)(ang  + drowbase + kt*128 + ecol);
        float4 d41 = *(const float4*)(dist + drowbase + kt*128 + ecol + 64);
        float4 g41 = *(const float4*)(ang  + drowbase + kt*128 + ecol + 64);
        float4 m40 = *(const float4*)(mask + b*S_LEN + kt*128 + ecol);
        float4 m41 = *(const float4*)(mask + b*S_LEN + kt*128 + ecol + 64);

        // MFMA: two 16x16 col-tiles per wave (ct and ct+4 within the 128)
        f32x4 acc0 = (f32x4){0.f,0.f,0.f,0.f};
        f32x4 acc1 = (f32x4){0.f,0.f,0.f,0.f};
        #pragma unroll
        for (int kk = 0; kk < 3; ++kk) {
            int kr0 = ct*16 + lh;
            bf16x8 kf0 = *(const bf16x8*)(KV + ((size_t)kr0*12 + ((kk*4+g) ^ ((kr0 >> 1) & 3)))*8);
            acc0 = MFMA16(qf[kk], kf0, acc0);
            int kr1 = (ct+4)*16 + lh;
            bf16x8 kf1 = *(const bf16x8*)(KV + ((size_t)kr1*12 + ((kk*4+g) ^ ((kr1 >> 1) & 3)))*8);
            acc1 = MFMA16(qf[kk], kf1, acc1);
        }
        __syncthreads();   // all K reads done -> safe to overwrite KV

        // ds_write next K tile (regs; vmem drained during MFMA)
        if (kt < 15) {
            #pragma unroll
            for (int i = 0; i < 3; ++i) {
                int idx = tid + 512*i;
                int r = idx / 12, c = idx - (idx/12)*12;
                *(float4*)(KV + ((size_t)r*12 + (c ^ ((r >> 1) & 3)))*8) = kreg[i];
            }
        }

        // epilogue col-half 0 (wave-local patch round-trip)
        {
            #pragma unroll
            for (int r = 0; r < 4; ++r)
                Sfme[(g*4 + r)*16 + lh] = acc0[r];
            float4 s4 = *(const float4*)&Sfme[prow*16 + pc*4];
            float e0 = __expf(s4.x*RSQRT_D + DW*d40.x + AW*g40.x + CB + (1.f - m40.x) * -10000.f);
            float e1 = __expf(s4.y*RSQRT_D + DW*d40.y + AW*g40.y + CB + (1.f - m40.y) * -10000.f);
            float e2 = __expf(s4.z*RSQRT_D + DW*d40.z + AW*g40.z + CB + (1.f - m40.z) * -10000.f);
            float e3 = __expf(s4.w*RSQRT_D + DW*d40.w + AW*g40.w + CB + (1.f - m40.w) * -10000.f);
            lpart += (e0 + e1) + (e2 + e3);
            U16x4 uk;
            uk.u[0] = f2bf(e0); uk.u[1] = f2bf(e1); uk.u[2] = f2bf(e2); uk.u[3] = f2bf(e3);
            *(uint2*)(Us + (size_t)(2*kt)*2048 + uoffA) = uk.v2;
        }
        // epilogue col-half 1
        {
            #pragma unroll
            for (int r = 0; r < 4; ++r)
                Sfme[(g*4 + r)*16 + lh] = acc1[r];
            float4 s4 = *(const float4*)&Sfme[prow*16 + pc*4];
            float e0 = __expf(s4.x*RSQRT_D + DW*d41.x + AW*g41.x + CB + (1.f - m41.x) * -10000.f);
            float e1 = __expf(s4.y*RSQRT_D + DW*d41.y + AW*g41.y + CB + (1.f - m41.y) * -10000.f);
            float e2 = __expf(s4.z*RSQRT_D + DW*d41.z + AW*g41.z + CB + (1.f - m41.z) * -10000.f);
            float e3 = __expf(s4.w*RSQRT_D + DW*d41.w + AW*g41.w + CB + (1.f - m41.w) * -10000.f);
            lpart += (e0 + e1) + (e2 + e3);
            U16x4 uk;
            uk.u[0] = f2bf(e0); uk.u[1] = f2bf(e1); uk.u[2] = f2bf(e2); uk.u[3] = f2bf(e3);
            *(uint2*)(Us + (size_t)(2*kt+1)*2048 + uoffA) = uk.v2;
        }
        __syncthreads();   // KV(kt+1) ready
    }

    // ---- l reduction (lanes pc within row, then across the 4 ct-waves) ----
    lpart += __shfl_xor(lpart, 1);
    lpart += __shfl_xor(lpart, 2);
    float* mLp = (float*)KV;            // K dead
    if (pc == 0) mLp[w*16 + prow] = lpart;
    __syncthreads();

    const int trowB = tid >> 4;         // 0..31
    const int c4B   = tid & 15;
    float invl_row = 1.0f / (mLp[((trowB>>4)*4 + 0)*16 + (trowB & 15)]
                           + mLp[((trowB>>4)*4 + 1)*16 + (trowB & 15)]
                           + mLp[((trowB>>4)*4 + 2)*16 + (trowB & 15)]
                           + mLp[((trowB>>4)*4 + 3)*16 + (trowB & 15)]);
    float ils[4];
    #pragma unroll
    for (int r = 0; r < 4; ++r) {
        int rr = g*4 + r;
        ils[r] = 1.0f / (mLp[(rt*4 + 0)*16 + rr] + mLp[(rt*4 + 1)*16 + rr]
                       + mLp[(rt*4 + 2)*16 + rr] + mLp[(rt*4 + 3)*16 + rr]);
    }
    __syncthreads();                    // mLp reads done before V0 overwrite

    // ---- stage V tile 0 (96 d-rows x 128 k) ----
    #pragma unroll
    for (int i = 0; i < 3; ++i) {
        int idx = tid + 512*i;
        int vr = idx >> 4, c = idx & 15;
        float4 v4 = *(const float4*)(vt + ((size_t)bh*HD + vr)*S_LEN + c*8);
        *(float4*)(KV + ((size_t)vr*16 + (c ^ (vr & 7)))*8) = v4;
    }
    __syncthreads();

    // ================= Phase B: probs = u*invl, ctx = (u @ V)*invl ==========
    const int uoffB = (trowB*8 + ((c4B >> 1) ^ (trowB & 7)))*8 + (c4B & 1)*4;
    const int dt1 = ct;
    const bool two = (ct < 2);
    const int dt2 = ct + 4;
    f32x4 accA = (f32x4){0.f,0.f,0.f,0.f};
    f32x4 accB = (f32x4){0.f,0.f,0.f,0.f};
    const int prowPV = rt*16 + lh;

    for (int kt = 0; kt < 16; ++kt) {
        // prefetch V(kt+1) into regs
        float4 vreg[3];
        if (kt < 15) {
            #pragma unroll
            for (int i = 0; i < 3; ++i) {
                int idx = tid + 512*i;
                int vr = idx >> 4, c = idx & 15;
                vreg[i] = *(const float4*)(vt + ((size_t)bh*HD + vr)*S_LEN + (kt+1)*128 + c*8);
            }
        }
        // probs writes (two 64-col halves) straight from LDS u
        {
            uint2 uu = *(const uint2*)(Us + (size_t)(2*kt)*2048 + uoffB);
            float4 p;
            p.x = bf2f(uu.x & 0xffffu)*invl_row; p.y = bf2f(uu.x >> 16)*invl_row;
            p.z = bf2f(uu.y & 0xffffu)*invl_row; p.w = bf2f(uu.y >> 16)*invl_row;
            *(float4*)(probs + ((size_t)bh*S_LEN + q0 + trowB)*S_LEN + kt*128 + c4B*4) = p;
            uu = *(const uint2*)(Us + (size_t)(2*kt+1)*2048 + uoffB);
            p.x = bf2f(uu.x & 0xffffu)*invl_row; p.y = bf2f(uu.x >> 16)*invl_row;
            p.z = bf2f(uu.y & 0xffffu)*invl_row; p.w = bf2f(uu.y >> 16)*invl_row;
            *(float4*)(probs + ((size_t)bh*S_LEN + q0 + trowB)*S_LEN + kt*128 + 64 + c4B*4) = p;
        }
        // PV MFMA over 128 k (4 k-chunups per d-tile)
        bf16x8 pa[4];
        #pragma unroll
        for (int kk = 0; kk < 4; ++kk) {
            int sub = 2*kt + (kk >> 1);
            int j = (kk & 1)*4 + g;
            pa[kk] = *(const bf16x8*)(Us + (size_t)sub*2048 + ((size_t)prowPV*8 + (j ^ (prowPV & 7)))*8);
        }
        #pragma unroll
        for (int kk = 0; kk < 4; ++kk) {
            int vr = dt1*16 + lh;
            bf16x8 vf = *(const bf16x8*)(KV + ((size_t)vr*16 + ((kk*4+g) ^ (vr & 7)))*8);
            accA = MFMA16(pa[kk], vf, accA);
        }
        if (two) {
            #pragma unroll
            for (int kk = 0; kk < 4; ++kk) {
                int vr = dt2*16 + lh;
                bf16x8 vf = *(const bf16x8*)(KV + ((size_t)vr*16 + ((kk*4+g) ^ (vr & 7)))*8);
                accB = MFMA16(pa[kk], vf, accB);
            }
        }
        __syncthreads();   // all V reads done
        if (kt < 15) {
            #pragma unroll
            for (int i = 0; i < 3; ++i) {
                int idx = tid + 512*i;
                int vr = idx >> 4, c = idx & 15;
                *(float4*)(KV + ((size_t)vr*16 + (c ^ (vr & 7)))*8) = vreg[i];
            }
        }
        __syncthreads();   // V(kt+1) ready
    }

    // ctx write (scaled by invl per row)
    #pragma unroll
    for (int r = 0; r < 4; ++r) {
        int qrow = q0 + rt*16 + g*4 + r;
        ctxb[((size_t)(b*S_LEN + qrow))*EMB + h*HD + dt1*16 + lh] = f2bf(accA[r] * ils[r]);
        if (two)
            ctxb[((size_t)(b*S_LEN + qrow))*EMB + h*HD + dt2*16 + lh] = f2bf(accB[r] * ils[r]);
    }
}

// ---------------------------------------------------------------------------
// Output proj MFMA (unchanged)
// ---------------------------------------------------------------------------
__global__ __launch_bounds__(256) void out_mfma_kernel(
    const u16* __restrict__ ctxb, const u16* __restrict__ WoT,
    const float* __restrict__ bo, const float* __restrict__ hs,
    float* __restrict__ res)
{
    __shared__ __align__(16) u16 As[64*64];
    __shared__ __align__(16) u16 Bs[64*64];
    const int tid = threadIdx.x;
    const int w = tid >> 6, lane = tid & 63, lh = lane & 15, g = lane >> 4;
    const int wm = w >> 1, wn = w & 1;
    const int row0 = blockIdx.y * 64, col0 = blockIdx.x * 64;

    f32x4 acc[2][2];
    #pragma unroll
    for (int i = 0; i < 2; ++i)
        #pragma unroll
        for (int j = 0; j < 2; ++j) acc[i][j] = (f32x4){0.f,0.f,0.f,0.f};

    for (int k0 = 0; k0 < EMB; k0 += 64) {
        __syncthreads();
        #pragma unroll
        for (int i = 0; i < 2; ++i) {
            int idx = tid + 256*i;
            int r = idx >> 3, c = idx & 7;
            float4 a4 = *(const float4*)(ctxb + (size_t)(row0 + r)*EMB + k0 + c*8);
            *(float4*)(As + ((size_t)r*8 + (c ^ (r & 7)))*8) = a4;
            float4 b4 = *(const float4*)(WoT + (size_t)(col0 + r)*EMB + k0 + c*8);
            *(float4*)(Bs + ((size_t)r*8 + (c ^ (r & 7)))*8) = b4;
        }
        __syncthreads();
        bf16x8 af[2][2], bfr[2][2];
        #pragma unroll
        for (int mt = 0; mt < 2; ++mt)
            #pragma unroll
            for (int kk = 0; kk < 2; ++kk) {
                int r = wm*32 + mt*16 + lh;
                af[mt][kk] = *(const bf16x8*)(As + ((size_t)r*8 + ((kk*4+g) ^ (lh & 7)))*8);
            }
        #pragma unroll
        for (int nt = 0; nt < 2; ++nt)
            #pragma unroll
            for (int kk = 0; kk < 2; ++kk) {
                int r = wn*32 + nt*16 + lh;
                bfr[nt][kk] = *(const bf16x8*)(Bs + ((size_t)r*8 + ((kk*4+g) ^ (lh & 7)))*8);
            }
        #pragma unroll
        for (int mt = 0; mt < 2; ++mt)
            #pragma unroll
            for (int nt = 0; nt < 2; ++nt)
                #pragma unroll
                for (int kk = 0; kk < 2; ++kk)
                    acc[mt][nt] = MFMA16(af[mt][kk], bfr[nt][kk], acc[mt][nt]);
    }

    #pragma unroll
    for (int mt = 0; mt < 2; ++mt)
        #pragma unroll
        for (int nt = 0; nt < 2; ++nt)
            #pragma unroll
            for (int r = 0; r < 4; ++r) {
                int tt = row0 + wm*32 + mt*16 + g*4 + r;
                int o  = col0 + wn*32 + nt*16 + lh;
                res[(size_t)tt*EMB + o] = acc[mt][nt][r] + bo[o] + hs[(size_t)tt*EMB + o];
            }
}

// ---------------------------------------------------------------------------
// LayerNorm in place over last dim 768. grid NTOK, block 256.
// ---------------------------------------------------------------------------
__device__ __forceinline__ float block_sum256(float v, float* red) {
    #pragma unroll
    for (int off = 32; off > 0; off >>= 1) v += __shfl_down(v, off);
    int lane = threadIdx.x & 63, w = threadIdx.x >> 6;
    __syncthreads();
    if (lane == 0) red[w] = v;
    __syncthreads();
    return red[0] + red[1] + red[2] + red[3];
}

__global__ __launch_bounds__(256) void ln_kernel(
    float* __restrict__ res, const float* __restrict__ gamma, const float* __restrict__ beta)
{
    const int t = blockIdx.x;
    float* row = res + (size_t)t * EMB;
    const int tid = threadIdx.x;
    __shared__ float red[4];

    float x0 = row[tid], x1 = row[tid + 256], x2 = row[tid + 512];
    float s = block_sum256(x0 + x1 + x2, red);
    float mu = s * (1.0f / (float)EMB);
    float d0 = x0 - mu, d1 = x1 - mu, d2 = x2 - mu;
    float sq = block_sum256(d0*d0 + d1*d1 + d2*d2, red);
    float var = sq * (1.0f / (float)EMB);
    float scale = rsqrtf(var + 1e-5f);

    row[tid]       = d0 * scale * gamma[tid]       + beta[tid];
    row[tid + 256] = d1 * scale * gamma[tid + 256] + beta[tid + 256];
    row[tid + 512] = d2 * scale * gamma[tid + 512] + beta[tid + 512];
}

// ---------------------------------------------------------------------------
extern "C" void kernel_launch(void* const* d_in, const int* in_sizes, int n_in,
                              void* d_out, int out_size, void* d_ws, size_t ws_size,
                              hipStream_t stream)
{
    (void)in_sizes; (void)n_in; (void)out_size; (void)ws_size;

    const float* hs   = (const float*)d_in[0];
    const float* dist = (const float*)d_in[1];
    const float* ang  = (const float*)d_in[2];
    const float* mask = (const float*)d_in[3];
    const float* Wq = (const float*)d_in[4];  const float* bq = (const float*)d_in[5];
    const float* Wk = (const float*)d_in[6];  const float* bk = (const float*)d_in[7];
    const float* Wv = (const float*)d_in[8];  const float* bv = (const float*)d_in[9];
    const float* dw = (const float*)d_in[10]; const float* db = (const float*)d_in[11];
    const float* aw = (const float*)d_in[12]; const float* ab = (const float*)d_in[13];
    const float* Wo = (const float*)d_in[14]; const float* bo = (const float*)d_in[15];
    const float* gamma = (const float*)d_in[16]; const float* beta = (const float*)d_in[17];

    float* out   = (float*)d_out;                      // [B,S,E]
    float* probs = out + (size_t)NTOK * EMB;           // [B,H,S,S]

    u16* hsb = (u16*)d_ws;
    u16* WqT = hsb + (size_t)NTOK*EMB;
    u16* WkT = WqT + (size_t)EMB*EMB;
    u16* WvT = WkT + (size_t)EMB*EMB;
    u16* WoT = WvT + (size_t)EMB*EMB;
    u16* qb  = WoT + (size_t)EMB*EMB;
    u16* kb  = qb + (size_t)NTOK*EMB;
    u16* vb  = kb + (size_t)NTOK*EMB;
    u16* vtb = vb + (size_t)NTOK*EMB;
    u16* ctxb = qb;                                    // reuse q region after attn

    cvt_bf16_kernel<<<dim3(NTOK*EMB/4/256), dim3(256), 0, stream>>>(hs, hsb, NTOK*EMB/4);
    transcvt_kernel<<<dim3(12,12), dim3(256), 0, stream>>>(Wq, WqT);
    transcvt_kernel<<<dim3(12,12), dim3(256), 0, stream>>>(Wk, WkT);
    transcvt_kernel<<<dim3(12,12), dim3(256), 0, stream>>>(Wv, WvT);
    transcvt_kernel<<<dim3(12,12), dim3(256), 0, stream>>>(Wo, WoT);

    qkv_mfma_kernel<<<dim3(EMB/64, NTOK/64, 3), dim3(256), 0, stream>>>(
        hsb, WqT, bq, WkT, bk, WvT, bv, qb, kb, vb);

    vtrans_kernel<<<dim3(S_LEN/64, BATCH*NH), dim3(256), 0, stream>>>(vb, vtb);

    fused_attn_kernel<<<dim3(S_LEN/32, BATCH*NH), dim3(512), 0, stream>>>(
        qb, kb, vtb, dist, ang, mask, dw, db, aw, ab, probs, ctxb);

    out_mfma_kernel<<<dim3(EMB/64, NTOK/64), dim3(256), 0, stream>>>(
        ctxb, WoT, bo, hs, out);

    ln_kernel<<<dim3(NTOK), dim3(256), 0, stream>>>(out, gamma, beta);
}

// Round 14
// 260.064 us; speedup vs baseline: 1.3355x; 1.3355x over previous
//
#include <hip/hip_runtime.h>
#include <math.h>

#define S_LEN 2048
#define BATCH 2
#define EMB 768
#define NH 8
#define HD 96
#define NTOK (BATCH*S_LEN)
#define RSQRT_D 0.10206207261596575f   // 1/sqrt(96)

typedef unsigned short u16;
typedef __attribute__((ext_vector_type(8))) short bf16x8;
typedef __attribute__((ext_vector_type(4))) float f32x4;

#define MFMA16(a,b,c) __builtin_amdgcn_mfma_f32_16x16x32_bf16(a,b,c,0,0,0)

__device__ __forceinline__ u16 f2bf(float f){
    unsigned u = __float_as_uint(f);
    return (u16)((u + 0x7fffu + ((u>>16)&1u)) >> 16);
}
__device__ __forceinline__ float bf2f(unsigned u){
    return __uint_as_float(u << 16);
}

union U16x8 { u16 u[8]; float4 f4; };
union U16x4 { u16 u[4]; uint2 v2; };

// ---------------------------------------------------------------------------
// f32 -> bf16 elementwise convert (vectorized x4)
// ---------------------------------------------------------------------------
__global__ __launch_bounds__(256) void cvt_bf16_kernel(
    const float* __restrict__ src, u16* __restrict__ dst, int n4)
{
    int i = blockIdx.x * 256 + threadIdx.x;
    if (i < n4) {
        float4 v = ((const float4*)src)[i];
        U16x4 o;
        o.u[0] = f2bf(v.x); o.u[1] = f2bf(v.y); o.u[2] = f2bf(v.z); o.u[3] = f2bf(v.w);
        *(uint2*)(dst + (size_t)i*4) = o.v2;
    }
}

// ---------------------------------------------------------------------------
// W[768][768] f32 -> Wt[n][k] bf16 (transpose + convert). grid (12,12), 256thr
// ---------------------------------------------------------------------------
__global__ __launch_bounds__(256) void transcvt_kernel(
    const float* __restrict__ W, u16* __restrict__ Wt)
{
    __shared__ float T[64][65];
    const int t = threadIdx.x;
    const int k0 = blockIdx.y * 64, n0 = blockIdx.x * 64;
    #pragma unroll
    for (int i = 0; i < 4; ++i) {
        int idx = t + 256*i;
        int r = idx >> 4, c4 = idx & 15;
        float4 v = *(const float4*)(W + (size_t)(k0 + r)*EMB + n0 + c4*4);
        T[r][c4*4+0] = v.x; T[r][c4*4+1] = v.y; T[r][c4*4+2] = v.z; T[r][c4*4+3] = v.w;
    }
    __syncthreads();
    #pragma unroll
    for (int i = 0; i < 2; ++i) {
        int idx = t + 256*i;
        int n = idx >> 3, c = idx & 7;
        U16x8 o;
        #pragma unroll
        for (int e = 0; e < 8; ++e) o.u[e] = f2bf(T[c*8+e][n]);
        *(float4*)(Wt + (size_t)(n0 + n)*EMB + k0 + c*8) = o.f4;
    }
}

// ---------------------------------------------------------------------------
// QKV projection MFMA (unchanged)
// ---------------------------------------------------------------------------
__global__ __launch_bounds__(256) void qkv_mfma_kernel(
    const u16* __restrict__ hsb,
    const u16* __restrict__ WqT, const float* __restrict__ bq,
    const u16* __restrict__ WkT, const float* __restrict__ bk,
    const u16* __restrict__ WvT, const float* __restrict__ bv,
    u16* __restrict__ qo, u16* __restrict__ ko, u16* __restrict__ vo)
{
    const u16* Wt; const float* bias; u16* out;
    if (blockIdx.z == 0)      { Wt = WqT; bias = bq; out = qo; }
    else if (blockIdx.z == 1) { Wt = WkT; bias = bk; out = ko; }
    else                      { Wt = WvT; bias = bv; out = vo; }

    __shared__ __align__(16) u16 As[64*64];
    __shared__ __align__(16) u16 Bs[64*64];
    const int tid = threadIdx.x;
    const int w = tid >> 6, lane = tid & 63, lh = lane & 15, g = lane >> 4;
    const int wm = w >> 1, wn = w & 1;
    const int row0 = blockIdx.y * 64, col0 = blockIdx.x * 64;

    f32x4 acc[2][2];
    #pragma unroll
    for (int i = 0; i < 2; ++i)
        #pragma unroll
        for (int j = 0; j < 2; ++j) acc[i][j] = (f32x4){0.f,0.f,0.f,0.f};

    for (int k0 = 0; k0 < EMB; k0 += 64) {
        __syncthreads();
        #pragma unroll
        for (int i = 0; i < 2; ++i) {
            int idx = tid + 256*i;
            int r = idx >> 3, c = idx & 7;
            float4 a4 = *(const float4*)(hsb + (size_t)(row0 + r)*EMB + k0 + c*8);
            *(float4*)(As + ((size_t)r*8 + (c ^ (r & 7)))*8) = a4;
            float4 b4 = *(const float4*)(Wt + (size_t)(col0 + r)*EMB + k0 + c*8);
            *(float4*)(Bs + ((size_t)r*8 + (c ^ (r & 7)))*8) = b4;
        }
        __syncthreads();
        bf16x8 af[2][2], bfr[2][2];
        #pragma unroll
        for (int mt = 0; mt < 2; ++mt)
            #pragma unroll
            for (int kk = 0; kk < 2; ++kk) {
                int r = wm*32 + mt*16 + lh;
                af[mt][kk] = *(const bf16x8*)(As + ((size_t)r*8 + ((kk*4+g) ^ (lh & 7)))*8);
            }
        #pragma unroll
        for (int nt = 0; nt < 2; ++nt)
            #pragma unroll
            for (int kk = 0; kk < 2; ++kk) {
                int r = wn*32 + nt*16 + lh;
                bfr[nt][kk] = *(const bf16x8*)(Bs + ((size_t)r*8 + ((kk*4+g) ^ (lh & 7)))*8);
            }
        #pragma unroll
        for (int mt = 0; mt < 2; ++mt)
            #pragma unroll
            for (int nt = 0; nt < 2; ++nt)
                #pragma unroll
                for (int kk = 0; kk < 2; ++kk)
                    acc[mt][nt] = MFMA16(af[mt][kk], bfr[nt][kk], acc[mt][nt]);
    }

    #pragma unroll
    for (int mt = 0; mt < 2; ++mt)
        #pragma unroll
        for (int nt = 0; nt < 2; ++nt)
            #pragma unroll
            for (int r = 0; r < 4; ++r) {
                int tt = row0 + wm*32 + mt*16 + g*4 + r;
                int o  = col0 + wn*32 + nt*16 + lh;
                float val = acc[mt][nt][r] + bias[o];
                int b = tt >> 11, s = tt & (S_LEN - 1);
                int h = o / HD, d = o - h*HD;
                out[((size_t)(b*NH + h)*S_LEN + s)*HD + d] = f2bf(val);
            }
}

// ---------------------------------------------------------------------------
// V transpose: vb[B,H,S,D] bf16 -> vt[B,H,D,S] bf16 (unchanged)
// ---------------------------------------------------------------------------
__global__ __launch_bounds__(256) void vtrans_kernel(
    const u16* __restrict__ vb, u16* __restrict__ vt)
{
    const int bh = blockIdx.y;
    const int s0 = blockIdx.x * 64;
    __shared__ __align__(16) u16 T[64*96];
    const int t = threadIdx.x;
    #pragma unroll
    for (int i = 0; i < 3; ++i) {
        int idx = t + 256*i;
        int s = idx / 12, c = idx % 12;
        float4 v = *(const float4*)(vb + ((size_t)bh*S_LEN + s0 + s)*HD + c*8);
        *(float4*)(T + ((size_t)s*12 + c)*8) = v;
    }
    __syncthreads();
    #pragma unroll
    for (int i = 0; i < 3; ++i) {
        int idx = t + 256*i;
        int d = idx >> 3, c = idx & 7;
        U16x8 o;
        #pragma unroll
        for (int e = 0; e < 8; ++e) o.u[e] = T[(size_t)(c*8+e)*HD + d];
        *(float4*)(vt + ((size_t)bh*HD + d)*S_LEN + s0 + c*8) = o.f4;
    }
}

// ---------------------------------------------------------------------------
// FUSED attention (round-10 structure, + s_setprio around MFMA clusters).
// QBLK=32, 512 threads (8 waves), grid (64,16). u stripe in LDS (128 KB).
// T14 pipeline: K/V tile kt+1 loaded into REGS during MFMA(kt); ds_write
// after the post-MFMA barrier — HBM latency hides under compute.
// ---------------------------------------------------------------------------
__global__ __launch_bounds__(512) void fused_attn_kernel(
    const u16* __restrict__ qbf, const u16* __restrict__ kbf,
    const u16* __restrict__ vt,
    const float* __restrict__ dist, const float* __restrict__ ang,
    const float* __restrict__ mask,
    const float* __restrict__ pdw, const float* __restrict__ pdb,
    const float* __restrict__ paw, const float* __restrict__ pab,
    float* __restrict__ probs, u16* __restrict__ ctxb)
{
    const int bh = blockIdx.y, b = bh >> 3, h = bh & 7;
    const int q0 = blockIdx.x * 32;
    const int tid = threadIdx.x;
    const int lane = tid & 63, w = tid >> 6, lh = lane & 15, g = lane >> 4;
    const int rt = w >> 2;              // row-tile (0,1)
    const int ct = w & 3;               // col-tile (QK) / d-tile base (PV)

    __shared__ __align__(16) u16 Us[32*2048];    // u stripe (128 KB)
    __shared__ __align__(16) u16 Ks[64*96];      // K tile (A) / V tile (B)
    __shared__ __align__(16) float Sf[32*68];    // acc staging; Q staged first
    __shared__ float mL[32];

    // staging index helpers
    const int kr_s = tid / 12, kc_s = tid - (tid / 12) * 12;        // K chunks
    const int kr2_s = (tid + 512) / 12, kc2_s = (tid + 512) - ((tid + 512) / 12) * 12;
    const int vr_s = tid >> 3, vc_s = tid & 7;                      // V chunks
    const int vr2_s = (tid + 512) >> 3, vc2_s = (tid + 512) & 7;

    // ---- prologue: stage Q (into Sf region) and K tile 0 ----
    u16* Qtmp = (u16*)Sf;
    if (tid < 384) {
        int r = tid / 12, c = tid % 12;
        float4 v = *(const float4*)(qbf + ((size_t)bh*S_LEN + q0 + r)*HD + c*8);
        *(float4*)(Qtmp + ((size_t)r*12 + (c ^ ((r >> 1) & 3)))*8) = v;
    }
    {
        float4 v = *(const float4*)(kbf + ((size_t)bh*S_LEN + kr_s)*HD + kc_s*8);
        *(float4*)(Ks + ((size_t)kr_s*12 + (kc_s ^ ((kr_s >> 1) & 3)))*8) = v;
        if (tid < 256) {
            float4 v2 = *(const float4*)(kbf + ((size_t)bh*S_LEN + kr2_s)*HD + kc2_s*8);
            *(float4*)(Ks + ((size_t)kr2_s*12 + (kc2_s ^ ((kr2_s >> 1) & 3)))*8) = v2;
        }
    }
    __syncthreads();
    bf16x8 qf[3];
    #pragma unroll
    for (int kk = 0; kk < 3; ++kk) {
        int r = rt*16 + lh;
        qf[kk] = *(const bf16x8*)(Qtmp + ((size_t)r*12 + ((kk*4+g) ^ ((r >> 1) & 3)))*8);
    }
    __syncthreads();   // protect Qtmp region before Sf f32 reuse

    const float DW = *pdw, AW = *paw, CB = *pdb + *pab;
    const int trow = tid >> 4;          // 0..31 (epilogue row)
    const int c4   = tid & 15;          // float4 col chunk
    const size_t drow = ((size_t)b*S_LEN + q0 + trow)*S_LEN;
    const int uoff = (trow*8 + ((c4 >> 1) ^ (trow & 7)))*8 + (c4 & 1)*4;

    float lpart = 0.f;

    // ================= Phase A: QK^T -> u = exp(s) into LDS =================
    for (int kt = 0; kt < 32; ++kt) {
        int coff = kt*64 + c4*4;
        // issue next-K reg loads (consumed post-barrier; hides under MFMA)
        float4 kreg0, kreg1;
        if (kt < 31) {
            kreg0 = *(const float4*)(kbf + ((size_t)bh*S_LEN + (kt+1)*64 + kr_s)*HD + kc_s*8);
            if (tid < 256)
                kreg1 = *(const float4*)(kbf + ((size_t)bh*S_LEN + (kt+1)*64 + kr2_s)*HD + kc2_s*8);
        }
        // bias/mask loads for this kt (consumed in epilogue)
        float4 d4 = *(const float4*)(dist + drow + coff);
        float4 g4 = *(const float4*)(ang  + drow + coff);
        float4 m4 = *(const float4*)(mask + b*S_LEN + coff);

        // MFMA over current Ks
        __builtin_amdgcn_s_setprio(1);
        f32x4 acc = (f32x4){0.f,0.f,0.f,0.f};
        #pragma unroll
        for (int kk = 0; kk < 3; ++kk) {
            int kr = ct*16 + lh;
            bf16x8 kf = *(const bf16x8*)(Ks + ((size_t)kr*12 + ((kk*4+g) ^ ((kr >> 1) & 3)))*8);
            acc = MFMA16(qf[kk], kf, acc);
        }
        __builtin_amdgcn_s_setprio(0);
        #pragma unroll
        for (int r = 0; r < 4; ++r)
            Sf[(rt*16 + g*4 + r)*68 + ct*16 + lh] = acc[r];
        __syncthreads();   // B2: Sf ready, all Ks reads done

        // epilogue: one row x 4 cols per thread
        float4 s4 = *(const float4*)&Sf[trow*68 + c4*4];
        float e0 = __expf(s4.x*RSQRT_D + DW*d4.x + AW*g4.x + CB + (1.f - m4.x) * -10000.f);
        float e1 = __expf(s4.y*RSQRT_D + DW*d4.y + AW*g4.y + CB + (1.f - m4.y) * -10000.f);
        float e2 = __expf(s4.z*RSQRT_D + DW*d4.z + AW*g4.z + CB + (1.f - m4.z) * -10000.f);
        float e3 = __expf(s4.w*RSQRT_D + DW*d4.w + AW*g4.w + CB + (1.f - m4.w) * -10000.f);
        lpart += (e0 + e1) + (e2 + e3);
        U16x4 uk;
        uk.u[0] = f2bf(e0); uk.u[1] = f2bf(e1); uk.u[2] = f2bf(e2); uk.u[3] = f2bf(e3);
        *(uint2*)(Us + (size_t)kt*2048 + uoff) = uk.v2;

        // ds_write next K tile (regs -> LDS; loads drained during MFMA+epi)
        if (kt < 31) {
            *(float4*)(Ks + ((size_t)kr_s*12 + (kc_s ^ ((kr_s >> 1) & 3)))*8) = kreg0;
            if (tid < 256)
                *(float4*)(Ks + ((size_t)kr2_s*12 + (kc2_s ^ ((kr2_s >> 1) & 3)))*8) = kreg1;
        }
        __syncthreads();   // B1: Ks(kt+1) ready
    }

    // row-sum reduce; stage V tile 0 into Ks region under the same barrier
    #pragma unroll
    for (int off = 1; off <= 8; off <<= 1) lpart += __shfl_xor(lpart, off);
    if (c4 == 0) mL[trow] = 1.0f / lpart;
    {
        float4 v4 = *(const float4*)(vt + ((size_t)bh*HD + vr_s)*S_LEN + vc_s*8);
        *(float4*)(Ks + ((size_t)vr_s*8 + (vc_s ^ (vr_s & 7)))*8) = v4;
        if (tid < 256) {
            float4 v42 = *(const float4*)(vt + ((size_t)bh*HD + vr2_s)*S_LEN + vc2_s*8);
            *(float4*)(Ks + ((size_t)vr2_s*8 + (vc2_s ^ (vr2_s & 7)))*8) = v42;
        }
    }
    __syncthreads();

    // ================= Phase B: probs = u*invl, ctx = (u @ V)*invl ==========
    const float invl_row = mL[trow];
    const int dt1 = ct;
    const bool two = (ct < 2);
    const int dt2 = ct + 4;
    f32x4 accA = (f32x4){0.f,0.f,0.f,0.f};
    f32x4 accB = (f32x4){0.f,0.f,0.f,0.f};

    for (int kt = 0; kt < 32; ++kt) {
        // issue next-V reg loads (hide under probs write + MFMA)
        float4 vreg0, vreg1;
        if (kt < 31) {
            vreg0 = *(const float4*)(vt + ((size_t)bh*HD + vr_s)*S_LEN + (kt+1)*64 + vc_s*8);
            if (tid < 256)
                vreg1 = *(const float4*)(vt + ((size_t)bh*HD + vr2_s)*S_LEN + (kt+1)*64 + vc2_s*8);
        }
        // probs write straight from LDS u
        {
            uint2 uu = *(const uint2*)(Us + (size_t)kt*2048 + uoff);
            float4 p;
            p.x = bf2f(uu.x & 0xffffu)*invl_row; p.y = bf2f(uu.x >> 16)*invl_row;
            p.z = bf2f(uu.y & 0xffffu)*invl_row; p.w = bf2f(uu.y >> 16)*invl_row;
            *(float4*)(probs + ((size_t)bh*S_LEN + q0 + trow)*S_LEN + kt*64 + c4*4) = p;
        }
        // PV MFMA on current V buffer
        int prow = rt*16 + lh;
        bf16x8 pa[2];
        #pragma unroll
        for (int kk = 0; kk < 2; ++kk)
            pa[kk] = *(const bf16x8*)(Us + (size_t)kt*2048 + ((size_t)prow*8 + ((kk*4+g) ^ (prow & 7)))*8);
        __builtin_amdgcn_s_setprio(1);
        #pragma unroll
        for (int kk = 0; kk < 2; ++kk) {
            int vr = dt1*16 + lh;
            bf16x8 vf = *(const bf16x8*)(Ks + ((size_t)vr*8 + ((kk*4+g) ^ (vr & 7)))*8);
            accA = MFMA16(pa[kk], vf, accA);
        }
        if (two) {
            #pragma unroll
            for (int kk = 0; kk < 2; ++kk) {
                int vr = dt2*16 + lh;
                bf16x8 vf = *(const bf16x8*)(Ks + ((size_t)vr*8 + ((kk*4+g) ^ (vr & 7)))*8);
                accB = MFMA16(pa[kk], vf, accB);
            }
        }
        __builtin_amdgcn_s_setprio(0);
        __syncthreads();   // all Vs reads done
        if (kt < 31) {
            *(float4*)(Ks + ((size_t)vr_s*8 + (vc_s ^ (vr_s & 7)))*8) = vreg0;
            if (tid < 256)
                *(float4*)(Ks + ((size_t)vr2_s*8 + (vc2_s ^ (vr2_s & 7)))*8) = vreg1;
        }
        __syncthreads();   // Vs(kt+1) ready
    }

    // ctx write (scaled by invl per row)
    float ils[4];
    #pragma unroll
    for (int r = 0; r < 4; ++r) ils[r] = mL[rt*16 + g*4 + r];
    #pragma unroll
    for (int r = 0; r < 4; ++r) {
        int qrow = q0 + rt*16 + g*4 + r;
        ctxb[((size_t)(b*S_LEN + qrow))*EMB + h*HD + dt1*16 + lh] = f2bf(accA[r] * ils[r]);
        if (two)
            ctxb[((size_t)(b*S_LEN + qrow))*EMB + h*HD + dt2*16 + lh] = f2bf(accB[r] * ils[r]);
    }
}

// ---------------------------------------------------------------------------
// Output proj MFMA (unchanged)
// ---------------------------------------------------------------------------
__global__ __launch_bounds__(256) void out_mfma_kernel(
    const u16* __restrict__ ctxb, const u16* __restrict__ WoT,
    const float* __restrict__ bo, const float* __restrict__ hs,
    float* __restrict__ res)
{
    __shared__ __align__(16) u16 As[64*64];
    __shared__ __align__(16) u16 Bs[64*64];
    const int tid = threadIdx.x;
    const int w = tid >> 6, lane = tid & 63, lh = lane & 15, g = lane >> 4;
    const int wm = w >> 1, wn = w & 1;
    const int row0 = blockIdx.y * 64, col0 = blockIdx.x * 64;

    f32x4 acc[2][2];
    #pragma unroll
    for (int i = 0; i < 2; ++i)
        #pragma unroll
        for (int j = 0; j < 2; ++j) acc[i][j] = (f32x4){0.f,0.f,0.f,0.f};

    for (int k0 = 0; k0 < EMB; k0 += 64) {
        __syncthreads();
        #pragma unroll
        for (int i = 0; i < 2; ++i) {
            int idx = tid + 256*i;
            int r = idx >> 3, c = idx & 7;
            float4 a4 = *(const float4*)(ctxb + (size_t)(row0 + r)*EMB + k0 + c*8);
            *(float4*)(As + ((size_t)r*8 + (c ^ (r & 7)))*8) = a4;
            float4 b4 = *(const float4*)(WoT + (size_t)(col0 + r)*EMB + k0 + c*8);
            *(float4*)(Bs + ((size_t)r*8 + (c ^ (r & 7)))*8) = b4;
        }
        __syncthreads();
        bf16x8 af[2][2], bfr[2][2];
        #pragma unroll
        for (int mt = 0; mt < 2; ++mt)
            #pragma unroll
            for (int kk = 0; kk < 2; ++kk) {
                int r = wm*32 + mt*16 + lh;
                af[mt][kk] = *(const bf16x8*)(As + ((size_t)r*8 + ((kk*4+g) ^ (lh & 7)))*8);
            }
        #pragma unroll
        for (int nt = 0; nt < 2; ++nt)
            #pragma unroll
            for (int kk = 0; kk < 2; ++kk) {
                int r = wn*32 + nt*16 + lh;
                bfr[nt][kk] = *(const bf16x8*)(Bs + ((size_t)r*8 + ((kk*4+g) ^ (lh & 7)))*8);
            }
        #pragma unroll
        for (int mt = 0; mt < 2; ++mt)
            #pragma unroll
            for (int nt = 0; nt < 2; ++nt)
                #pragma unroll
                for (int kk = 0; kk < 2; ++kk)
                    acc[mt][nt] = MFMA16(af[mt][kk], bfr[nt][kk], acc[mt][nt]);
    }

    #pragma unroll
    for (int mt = 0; mt < 2; ++mt)
        #pragma unroll
        for (int nt = 0; nt < 2; ++nt)
            #pragma unroll
            for (int r = 0; r < 4; ++r) {
                int tt = row0 + wm*32 + mt*16 + g*4 + r;
                int o  = col0 + wn*32 + nt*16 + lh;
                res[(size_t)tt*EMB + o] = acc[mt][nt][r] + bo[o] + hs[(size_t)tt*EMB + o];
            }
}

// ---------------------------------------------------------------------------
// LayerNorm in place over last dim 768. grid NTOK, block 256.
// ---------------------------------------------------------------------------
__device__ __forceinline__ float block_sum256(float v, float* red) {
    #pragma unroll
    for (int off = 32; off > 0; off >>= 1) v += __shfl_down(v, off);
    int lane = threadIdx.x & 63, w = threadIdx.x >> 6;
    __syncthreads();
    if (lane == 0) red[w] = v;
    __syncthreads();
    return red[0] + red[1] + red[2] + red[3];
}

__global__ __launch_bounds__(256) void ln_kernel(
    float* __restrict__ res, const float* __restrict__ gamma, const float* __restrict__ beta)
{
    const int t = blockIdx.x;
    float* row = res + (size_t)t * EMB;
    const int tid = threadIdx.x;
    __shared__ float red[4];

    float x0 = row[tid], x1 = row[tid + 256], x2 = row[tid + 512];
    float s = block_sum256(x0 + x1 + x2, red);
    float mu = s * (1.0f / (float)EMB);
    float d0 = x0 - mu, d1 = x1 - mu, d2 = x2 - mu;
    float sq = block_sum256(d0*d0 + d1*d1 + d2*d2, red);
    float var = sq * (1.0f / (float)EMB);
    float scale = rsqrtf(var + 1e-5f);

    row[tid]       = d0 * scale * gamma[tid]       + beta[tid];
    row[tid + 256] = d1 * scale * gamma[tid + 256] + beta[tid + 256];
    row[tid + 512] = d2 * scale * gamma[tid + 512] + beta[tid + 512];
}

// ---------------------------------------------------------------------------
extern "C" void kernel_launch(void* const* d_in, const int* in_sizes, int n_in,
                              void* d_out, int out_size, void* d_ws, size_t ws_size,
                              hipStream_t stream)
{
    (void)in_sizes; (void)n_in; (void)out_size; (void)ws_size;

    const float* hs   = (const float*)d_in[0];
    const float* dist = (const float*)d_in[1];
    const float* ang  = (const float*)d_in[2];
    const float* mask = (const float*)d_in[3];
    const float* Wq = (const float*)d_in[4];  const float* bq = (const float*)d_in[5];
    const float* Wk = (const float*)d_in[6];  const float* bk = (const float*)d_in[7];
    const float* Wv = (const float*)d_in[8];  const float* bv = (const float*)d_in[9];
    const float* dw = (const float*)d_in[10]; const float* db = (const float*)d_in[11];
    const float* aw = (const float*)d_in[12]; const float* ab = (const float*)d_in[13];
    const float* Wo = (const float*)d_in[14]; const float* bo = (const float*)d_in[15];
    const float* gamma = (const float*)d_in[16]; const float* beta = (const float*)d_in[17];

    float* out   = (float*)d_out;                      // [B,S,E]
    float* probs = out + (size_t)NTOK * EMB;           // [B,H,S,S]

    u16* hsb = (u16*)d_ws;
    u16* WqT = hsb + (size_t)NTOK*EMB;
    u16* WkT = WqT + (size_t)EMB*EMB;
    u16* WvT = WkT + (size_t)EMB*EMB;
    u16* WoT = WvT + (size_t)EMB*EMB;
    u16* qb  = WoT + (size_t)EMB*EMB;
    u16* kb  = qb + (size_t)NTOK*EMB;
    u16* vb  = kb + (size_t)NTOK*EMB;
    u16* vtb = vb + (size_t)NTOK*EMB;
    u16* ctxb = qb;                                    // reuse q region after attn

    cvt_bf16_kernel<<<dim3(NTOK*EMB/4/256), dim3(256), 0, stream>>>(hs, hsb, NTOK*EMB/4);
    transcvt_kernel<<<dim3(12,12), dim3(256), 0, stream>>>(Wq, WqT);
    transcvt_kernel<<<dim3(12,12), dim3(256), 0, stream>>>(Wk, WkT);
    transcvt_kernel<<<dim3(12,12), dim3(256), 0, stream>>>(Wv, WvT);
    transcvt_kernel<<<dim3(12,12), dim3(256), 0, stream>>>(Wo, WoT);

    qkv_mfma_kernel<<<dim3(EMB/64, NTOK/64, 3), dim3(256), 0, stream>>>(
        hsb, WqT, bq, WkT, bk, WvT, bv, qb, kb, vb);

    vtrans_kernel<<<dim3(S_LEN/64, BATCH*NH), dim3(256), 0, stream>>>(vb, vtb);

    fused_attn_kernel<<<dim3(S_LEN/32, BATCH*NH), dim3(512), 0, stream>>>(
        qb, kb, vtb, dist, ang, mask, dw, db, aw, ab, probs, ctxb);

    out_mfma_kernel<<<dim3(EMB/64, NTOK/64), dim3(256), 0, stream>>>(
        ctxb, WoT, bo, hs, out);

    ln_kernel<<<dim3(NTOK), dim3(256), 0, stream>>>(out, gamma, beta);
}